// Round 2
// baseline (924.231 us; speedup 1.0000x reference)
//
#include <hip/hip_runtime.h>
#include <hip/hip_bf16.h>

#define N 512
#define CS 1024
#define CZ 128
#define H 12
#define HD 16

// ---------------------------------------------------------------------------
// dtype sniff: 1 if buffer holds f32, 0 if bf16. Reads 32 16-bit words.
// bf16 N(0,1): exponent field in ~[117,130]. f32 data read as bf16: half the
// words are mantissa fragments with uniform-random exponent bits -> flagged.
// ---------------------------------------------------------------------------
__device__ int sniff_f32(const unsigned short* p) {
    int bad = 0;
    for (int i = 0; i < 32; ++i) {
        unsigned short u = p[i];
        int e = (u >> 7) & 0xFF;
        if (e == 0xFF || e >= 141 || (e <= 27 && (u & 0x7FFFu) != 0)) bad++;
    }
    return bad > 0;
}

__device__ __forceinline__ float ld(const void* p, int i, int f32) {
    return f32 ? ((const float*)p)[i]
               : __bfloat162float(((const __hip_bfloat16*)p)[i]);
}

// ---------------------------------------------------------------------------
// K1: q/k/v projections. grid (512 rows, 3 col-blocks) x 192 threads.
// q: n*192 + h*16 + d ; k,v same layout.
// ---------------------------------------------------------------------------
__global__ void proj_qkv(const void* s, const void* Wq, const void* bq,
                         const void* Wkv, const void* bkv,
                         float* q, float* k, float* v)
{
    __shared__ float sL[CS];
    __shared__ int flag;
    int t = threadIdx.x;
    int i = blockIdx.x;
    int col = blockIdx.y * 192 + t;     // [0,576)
    if (t == 0) flag = sniff_f32((const unsigned short*)s);
    __syncthreads();
    int f32 = flag;
    for (int idx = t; idx < CS; idx += 192) sL[idx] = ld(s, i * CS + idx, f32);
    __syncthreads();
    const void* W; const void* bv; int c, ldim;
    if (col < 192) { W = Wq;  bv = bq;  c = col;       ldim = 192; }
    else           { W = Wkv; bv = bkv; c = col - 192; ldim = 384; }
    float acc = ld(bv, c, f32);
    for (int kk = 0; kk < CS; ++kk) acc += sL[kk] * ld(W, kk * ldim + c, f32);
    if (col < 192) q[i * 192 + col] = acc;
    else {
        int cc = col - 192, h = cc >> 5, t2 = cc & 31;
        if (t2 < 16) k[i * 192 + h * 16 + t2] = acc;
        else         v[i * 192 + h * 16 + (t2 - 16)] = acc;
    }
}

// ---------------------------------------------------------------------------
// K2: point projections + rotation fused. grid 512 x 576 threads.
// Raw cols: qp_raw [0,144) (x|y|z blocks of 48), kvp_raw [144,576) (x|y|z of 144).
// Outputs: qp/kp n*144 + h*12 + p*3 + c ; vp n*288 + h*24 + p*3 + c (global frame)
// ---------------------------------------------------------------------------
__global__ void proj_pts(const void* s, const void* Wqp, const void* bqp,
                         const void* Wkvp, const void* bkvp,
                         const void* rot, const void* trans,
                         float* qp, float* kp, float* vp)
{
    __shared__ float sL[CS];
    __shared__ float rawL[576];
    __shared__ float R[9], T[3];
    __shared__ int flag;
    int t = threadIdx.x;     // 576
    int i = blockIdx.x;
    if (t == 0) flag = sniff_f32((const unsigned short*)s);
    __syncthreads();
    int f32 = flag;
    for (int idx = t; idx < CS; idx += 576) sL[idx] = ld(s, i * CS + idx, f32);
    if (t < 9) R[t] = ld(rot, i * 9 + t, f32);
    if (t >= 16 && t < 19) T[t - 16] = ld(trans, i * 3 + (t - 16), f32);
    __syncthreads();
    const void* W; const void* bv; int c, ldim;
    if (t < 144) { W = Wqp;  bv = bqp;  c = t;       ldim = 144; }
    else         { W = Wkvp; bv = bkvp; c = t - 144; ldim = 432; }
    float acc = ld(bv, c, f32);
    for (int kk = 0; kk < CS; ++kk) acc += sL[kk] * ld(W, kk * ldim + c, f32);
    rawL[t] = acc;
    __syncthreads();
    if (t < 192) {
        float x, y, zc;
        if (t < 48) { x = rawL[t];        y = rawL[48 + t];   zc = rawL[96 + t]; }
        else { int pk = t - 48;
               x = rawL[144 + pk]; y = rawL[288 + pk]; zc = rawL[432 + pk]; }
        float rx = R[0]*x + R[1]*y + R[2]*zc + T[0];
        float ry = R[3]*x + R[4]*y + R[5]*zc + T[1];
        float rz = R[6]*x + R[7]*y + R[8]*zc + T[2];
        if (t < 48) {
            int h = t >> 2, pp = t & 3, b = i * 144 + h * 12 + pp * 3;
            qp[b] = rx; qp[b + 1] = ry; qp[b + 2] = rz;
        } else {
            int pk = t - 48, h = pk / 12, idx = pk % 12;
            if (idx < 4) { int b = i * 144 + h * 12 + idx * 3;
                           kp[b] = rx; kp[b + 1] = ry; kp[b + 2] = rz; }
            else         { int b = i * 288 + h * 24 + (idx - 4) * 3;
                           vp[b] = rx; vp[b + 1] = ry; vp[b + 2] = rz; }
        }
    }
}

// ---------------------------------------------------------------------------
// K3: fused bias + logits + softmax + (o, o_pt, o_pair) per query row i.
// grid 512 x 512 threads. att lives only in LDS (24KB). No bias/att in ws.
// cat layout: o(0..191) x(192..287) y(288..383) z(384..479) norm(480..575) pair(576..2111)
// ---------------------------------------------------------------------------
__global__ void attn_fused(const float* q, const float* k, const float* v,
                           const float* qp, const float* kp, const float* vp,
                           const void* z, const void* Wb, const void* bb,
                           const void* head_w, const void* mask,
                           const void* rot, const void* trans, const void* s,
                           float* cat)
{
    __shared__ float attL[H * N];        // 24 KB
    __shared__ float WbL[CZ * H];        // 6 KB
    __shared__ float pairP[4 * H * CZ];  // 24 KB
    __shared__ float qL[192], qpL[144];
    __shared__ float RL[9], TL[3], bbL[H], hwL[H];
    __shared__ float miS;
    __shared__ int flag;
    int t = threadIdx.x;   // 512
    int i = blockIdx.x;
    if (t == 0) flag = sniff_f32((const unsigned short*)s);
    __syncthreads();
    int f32 = flag;
    for (int idx = t; idx < CZ * H; idx += 512) WbL[idx] = ld(Wb, idx, f32);
    if (t < 192) qL[t] = q[i * 192 + t];
    else if (t < 336) qpL[t - 192] = qp[i * 144 + (t - 192)];
    else if (t < 345) RL[t - 336] = ld(rot, i * 9 + (t - 336), f32);
    else if (t < 348) TL[t - 345] = ld(trans, i * 3 + (t - 345), f32);
    else if (t < 360) bbL[t - 348] = ld(bb, t - 348, f32);
    else if (t < 372) {
        float x = ld(head_w, t - 360, f32);
        float sp = (x > 20.f) ? x : log1pf(expf(x));
        hwL[t - 360] = sp * 0.13608276348795434f;   // softplus * sqrt(1/54)
    }
    else if (t == 372) miS = ld(mask, i, f32);
    __syncthreads();

    // ---- Phase B: logits for all heads, thread = key index j ----
    {
        int j = t;
        float bj[H];
        #pragma unroll
        for (int h = 0; h < H; ++h) bj[h] = bbL[h];
        int zbase = (i * N + j) * CZ;
        for (int c = 0; c < CZ; ++c) {
            float zc = ld(z, zbase + c, f32);
            #pragma unroll
            for (int h = 0; h < H; ++h) bj[h] += zc * WbL[c * H + h];
        }
        float mj = ld(mask, j, f32);
        float mterm = 100000.0f * (miS * mj - 1.0f);
        for (int h = 0; h < H; ++h) {
            float qk = 0.f;
            #pragma unroll
            for (int d = 0; d < HD; ++d) qk += qL[h * 16 + d] * k[j * 192 + h * 16 + d];
            float pt = 0.f;
            int kb = j * 144 + h * 12;
            #pragma unroll
            for (int p = 0; p < 4; ++p) {
                float dx = qpL[h * 12 + p * 3 + 0] - kp[kb + p * 3 + 0];
                float dy = qpL[h * 12 + p * 3 + 1] - kp[kb + p * 3 + 1];
                float dz = qpL[h * 12 + p * 3 + 2] - kp[kb + p * 3 + 2];
                pt += dx * dx + dy * dy + dz * dz;
            }
            attL[h * N + j] = qk * 0.14433756729740643f     // sqrt(1/48)
                            + 0.5773502691896258f * bj[h]   // sqrt(1/3)
                            - 0.5f * hwL[h] * pt + mterm;
        }
    }
    __syncthreads();

    // ---- Phase C: softmax per head (one wave per head) ----
    {
        int w = t >> 6, l = t & 63;
        for (int h = w; h < H; h += 8) {
            float av[8];
            #pragma unroll
            for (int kk = 0; kk < 8; ++kk) av[kk] = attL[h * N + kk * 64 + l];
            float m = av[0];
            #pragma unroll
            for (int kk = 1; kk < 8; ++kk) m = fmaxf(m, av[kk]);
            for (int off = 1; off < 64; off <<= 1) m = fmaxf(m, __shfl_xor(m, off));
            float ssum = 0.f;
            #pragma unroll
            for (int kk = 0; kk < 8; ++kk) { av[kk] = __expf(av[kk] - m); ssum += av[kk]; }
            for (int off = 1; off < 64; off <<= 1) ssum += __shfl_xor(ssum, off);
            float inv = 1.0f / ssum;
            #pragma unroll
            for (int kk = 0; kk < 8; ++kk) attL[h * N + kk * 64 + l] = av[kk] * inv;
        }
    }
    __syncthreads();

    // ---- Phase D1: o = a@v (192 thr), o_pt + inv-frame + norm (96 thr) ----
    if (t < 192) {
        int h = t >> 4, d = t & 15;
        float acc = 0.f;
        for (int j = 0; j < N; ++j) acc += attL[h * N + j] * v[j * 192 + h * 16 + d];
        cat[i * 2112 + t] = acc;
    } else if (t < 288) {
        int hp = t - 192, h = hp >> 3, p = hp & 7;
        float ax = 0, ay = 0, az = 0;
        for (int j = 0; j < N; ++j) {
            float a_ = attL[h * N + j];
            int b2 = j * 288 + h * 24 + p * 3;
            ax += a_ * vp[b2]; ay += a_ * vp[b2 + 1]; az += a_ * vp[b2 + 2];
        }
        float gx = ax - TL[0], gy = ay - TL[1], gz = az - TL[2];
        float lx = RL[0]*gx + RL[3]*gy + RL[6]*gz;   // R^T
        float ly = RL[1]*gx + RL[4]*gy + RL[7]*gz;
        float lz = RL[2]*gx + RL[5]*gy + RL[8]*gz;
        float nrm = sqrtf(lx*lx + ly*ly + lz*lz + 1e-8f);
        cat[i * 2112 + 192 + hp] = lx;
        cat[i * 2112 + 288 + hp] = ly;
        cat[i * 2112 + 384 + hp] = lz;
        cat[i * 2112 + 480 + hp] = nrm;
    }

    // ---- Phase D2: o_pair = a @ z[i]  (all 512 threads, 4 j-quarters) ----
    {
        int quarter = t >> 7, c = t & 127;
        float pacc[H];
        #pragma unroll
        for (int h = 0; h < H; ++h) pacc[h] = 0.f;
        int j0 = quarter * 128;
        for (int j = j0; j < j0 + 128; ++j) {
            float zc = ld(z, (i * N + j) * CZ + c, f32);
            #pragma unroll
            for (int h = 0; h < H; ++h) pacc[h] += attL[h * N + j] * zc;
        }
        #pragma unroll
        for (int h = 0; h < H; ++h) pairP[quarter * (H * CZ) + h * CZ + c] = pacc[h];
    }
    __syncthreads();
    for (int idx = t; idx < H * CZ; idx += 512)
        cat[i * 2112 + 576 + idx] =
            pairP[idx] + pairP[1536 + idx] + pairP[3072 + idx] + pairP[4608 + idx];
}

// ---------------------------------------------------------------------------
// K4: out = cat @ Wout + bout. grid (4, 512) x 256.
// ---------------------------------------------------------------------------
__global__ void final_gemm(const float* cat, const void* Wout, const void* bout,
                           void* out, const void* s)
{
    __shared__ float catL[2112];
    __shared__ int flag;
    int t = threadIdx.x;
    int i = blockIdx.y;
    int c = blockIdx.x * 256 + t;
    if (t == 0) flag = sniff_f32((const unsigned short*)s);
    __syncthreads();
    int f32 = flag;
    for (int idx = t; idx < 2112; idx += 256) catL[idx] = cat[i * 2112 + idx];
    __syncthreads();
    float acc = ld(bout, c, f32);
    for (int kk = 0; kk < 2112; ++kk) acc += catL[kk] * ld(Wout, kk * CS + c, f32);
    if (f32) ((float*)out)[i * CS + c] = acc;
    else     ((__hip_bfloat16*)out)[i * CS + c] = __float2bfloat16(acc);
}

extern "C" void kernel_launch(void* const* d_in, const int* in_sizes, int n_in,
                              void* d_out, int out_size, void* d_ws, size_t ws_size,
                              hipStream_t stream)
{
    const void* s      = d_in[0];
    const void* z      = d_in[1];
    const void* rot    = d_in[2];
    const void* trans  = d_in[3];
    const void* mask   = d_in[4];
    const void* Wq     = d_in[5];  const void* bq   = d_in[6];
    const void* Wkv    = d_in[7];  const void* bkv  = d_in[8];
    const void* Wqp    = d_in[9];  const void* bqp  = d_in[10];
    const void* Wkvp   = d_in[11]; const void* bkvp = d_in[12];
    const void* Wb     = d_in[13]; const void* bb   = d_in[14];
    const void* head_w = d_in[15];
    const void* Wout   = d_in[16]; const void* bout = d_in[17];

    float* w   = (float*)d_ws;          // total 1,671,168 floats = 6.4 MB
    float* q   = w;                     // 512*192
    float* k   = q  + 98304;
    float* v   = k  + 98304;
    float* qp  = v  + 98304;            // 512*144
    float* kp  = qp + 73728;
    float* vp  = kp + 73728;            // 512*288
    float* cat = vp + 147456;           // 512*2112
    (void)ws_size; (void)in_sizes; (void)n_in; (void)out_size;

    proj_qkv  <<<dim3(512, 3), 192, 0, stream>>>(s, Wq, bq, Wkv, bkv, q, k, v);
    proj_pts  <<<512, 576, 0, stream>>>(s, Wqp, bqp, Wkvp, bkvp, rot, trans, qp, kp, vp);
    attn_fused<<<512, 512, 0, stream>>>(q, k, v, qp, kp, vp, z, Wb, bb, head_w, mask,
                                        rot, trans, s, cat);
    final_gemm<<<dim3(4, 512), 256, 0, stream>>>(cat, Wout, bout, d_out, s);
}